// Round 8
// baseline (374.882 us; speedup 1.0000x reference)
//
#include <hip/hip_runtime.h>
#include <hip/hip_bf16.h>

// Problem constants (fixed by reference setup_inputs)
constexpr int HEADS = 8;
constexpr int B = 4;
constexpr int BH = B * HEADS;   // 32
constexpr int T = 16384;
constexpr int DH = 64;
constexpr int NB = 128;          // MAX_BUCKETS
constexpr int DIM = 128;         // 2*DH
constexpr float EPS = 1e-6f;
constexpr float INV_TEMP = 1.0f / 0.7f;

// ---------------------------------------------------------------------------
// K0: bucket boundaries. seg[b] is sorted; start[b][m] = first index i with
// seg[b][i] >= m, for m in [0,128]. start[b][128] = T. One block per b;
// each thread scans transition points (prev=seg[i-1], cur=seg[i]) and fills
// start[b][v]=i for v in (prev, cur]. Each v written by exactly one i.
// ---------------------------------------------------------------------------
__global__ __launch_bounds__(256) void k_bounds(
    const int* __restrict__ seg, int* __restrict__ start) {
  const int b = blockIdx.x;
  const int tid = threadIdx.x;
  const int* s = seg + (size_t)b * T;
  for (int i = tid; i <= T; i += 256) {
    const int prev = (i == 0) ? -1 : s[i - 1];
    const int cur = (i == T) ? NB : s[i];
    for (int v = prev + 1; v <= cur; ++v) start[b * (NB + 1) + v] = i;
  }
}

// ---------------------------------------------------------------------------
// K1: bucket sums. One wave per (bh, m): dense branch-free reduction of
// q[bh][start..end) and k[bh][start..end) into x[bh][m][0:128].
// Lanes 0..31 sum q (float2 per lane), lanes 32..63 sum k. 8-deep unroll
// with independent addresses -> 8 loads in flight per wave. No atomics,
// no memset: every output element written exactly once.
// ---------------------------------------------------------------------------
__global__ __launch_bounds__(256) void k_bucketsum(
    const float* __restrict__ q, const float* __restrict__ k,
    const int* __restrict__ start, float* __restrict__ x) {
  const int wave = threadIdx.x >> 6;
  const int lane = threadIdx.x & 63;
  const int p = blockIdx.x * 4 + wave;   // pair index, 0..4095
  const int bh = p >> 7;
  const int m = p & 127;
  const int b = bh >> 3;

  const int s = start[b * (NB + 1) + m];
  const int e = start[b * (NB + 1) + m + 1];

  const int half = lane >> 5;            // 0 = q, 1 = k
  const int li = lane & 31;              // float2 index within row
  const float2* src =
      (const float2*)((half ? k : q) + (size_t)bh * T * DH) + li;

  float2 a = make_float2(0.f, 0.f);
  int t = s;
  for (; t + 8 <= e; t += 8) {
    float2 v0 = src[(size_t)(t + 0) * 32];
    float2 v1 = src[(size_t)(t + 1) * 32];
    float2 v2 = src[(size_t)(t + 2) * 32];
    float2 v3 = src[(size_t)(t + 3) * 32];
    float2 v4 = src[(size_t)(t + 4) * 32];
    float2 v5 = src[(size_t)(t + 5) * 32];
    float2 v6 = src[(size_t)(t + 6) * 32];
    float2 v7 = src[(size_t)(t + 7) * 32];
    float2 s01 = make_float2(v0.x + v1.x, v0.y + v1.y);
    float2 s23 = make_float2(v2.x + v3.x, v2.y + v3.y);
    float2 s45 = make_float2(v4.x + v5.x, v4.y + v5.y);
    float2 s67 = make_float2(v6.x + v7.x, v6.y + v7.y);
    float2 s03 = make_float2(s01.x + s23.x, s01.y + s23.y);
    float2 s47 = make_float2(s45.x + s67.x, s45.y + s67.y);
    a.x += s03.x + s47.x;
    a.y += s03.y + s47.y;
  }
  for (; t < e; ++t) {
    const float2 v = src[(size_t)t * 32];
    a.x += v.x;
    a.y += v.y;
  }

  float2* op = (float2*)(x + ((size_t)bh * NB + m) * DIM + half * DH) + li;
  *op = a;
}

// ---------------------------------------------------------------------------
// K2a: R = relu(x @ W), r0 = (log(R+eps) + gumbel)/temp. One block per
// (bh, 16-row chunk). x rows staged in LDS; W streamed from L1/L2.
// ---------------------------------------------------------------------------
__global__ __launch_bounds__(256) void k_matmul(
    const float* __restrict__ x, const float* __restrict__ linear,
    const float* __restrict__ gumbel, float* __restrict__ r0) {
  const int bh = blockIdx.y;
  const int n0 = blockIdx.x * 16;
  const int h = bh & 7;                  // bh % HEADS
  const int tid = threadIdx.x;

  __shared__ float xs[16][DIM];          // 8 KB

  const float4* xp = (const float4*)(x + ((size_t)bh * NB + n0) * DIM);
  for (int i = tid; i < 16 * 32; i += 256) {
    const float4 v = xp[i];
    const int n = i >> 5, d4 = i & 31;
    xs[n][d4 * 4 + 0] = v.x;
    xs[n][d4 * 4 + 1] = v.y;
    xs[n][d4 * 4 + 2] = v.z;
    xs[n][d4 * 4 + 3] = v.w;
  }
  __syncthreads();

  const int mt = tid & 31;               // output col float4
  const int rp = tid >> 5;               // 0..7 row pair
  const int ra = rp * 2;

  float4 a0 = make_float4(0.f, 0.f, 0.f, 0.f);
  float4 a1 = make_float4(0.f, 0.f, 0.f, 0.f);
  const float4* Wp = (const float4*)(linear + (size_t)h * DIM * NB);
  for (int d4 = 0; d4 < 32; d4++) {
    const float4 xv0 = *(const float4*)&xs[ra][d4 * 4];
    const float4 xv1 = *(const float4*)&xs[ra + 1][d4 * 4];
    const float4 w0 = Wp[(d4 * 4 + 0) * 32 + mt];
    const float4 w1 = Wp[(d4 * 4 + 1) * 32 + mt];
    const float4 w2 = Wp[(d4 * 4 + 2) * 32 + mt];
    const float4 w3 = Wp[(d4 * 4 + 3) * 32 + mt];
    a0.x += xv0.x * w0.x + xv0.y * w1.x + xv0.z * w2.x + xv0.w * w3.x;
    a0.y += xv0.x * w0.y + xv0.y * w1.y + xv0.z * w2.y + xv0.w * w3.y;
    a0.z += xv0.x * w0.z + xv0.y * w1.z + xv0.z * w2.z + xv0.w * w3.z;
    a0.w += xv0.x * w0.w + xv0.y * w1.w + xv0.z * w2.w + xv0.w * w3.w;
    a1.x += xv1.x * w0.x + xv1.y * w1.x + xv1.z * w2.x + xv1.w * w3.x;
    a1.y += xv1.x * w0.y + xv1.y * w1.y + xv1.z * w2.y + xv1.w * w3.y;
    a1.z += xv1.x * w0.z + xv1.y * w1.z + xv1.z * w2.z + xv1.w * w3.z;
    a1.w += xv1.x * w0.w + xv1.y * w1.w + xv1.z * w2.w + xv1.w * w3.w;
  }

  const float4* gp = (const float4*)(gumbel + ((size_t)bh * NB + n0) * NB);
  float4* op = (float4*)(r0 + ((size_t)bh * NB + n0) * NB);

  auto xform = [](float a, float u) {
    const float R = fmaxf(a, 0.f);
    const float g = -__logf(-__logf(u + EPS) + EPS);
    return (__logf(R + EPS) + g) * INV_TEMP;
  };
  {
    const float4 u = gp[(size_t)ra * 32 + mt];
    float4 o;
    o.x = xform(a0.x, u.x); o.y = xform(a0.y, u.y);
    o.z = xform(a0.z, u.z); o.w = xform(a0.w, u.w);
    op[(size_t)ra * 32 + mt] = o;
  }
  {
    const float4 u = gp[(size_t)(ra + 1) * 32 + mt];
    float4 o;
    o.x = xform(a1.x, u.x); o.y = xform(a1.y, u.y);
    o.z = xform(a1.z, u.z); o.w = xform(a1.w, u.w);
    op[(size_t)(ra + 1) * 32 + mt] = o;
  }
}

// ---------------------------------------------------------------------------
// K2b: 8 Sinkhorn iterations + exp. One block (512 threads) per bh.
// Row state in REGISTERS: thread (row=tid>>2, qp=tid&3) owns r[row][qp*32+j].
// Per iter: row-LSE pure regs+shfl -> write to LDS image -> staggered
// conflict-free column read -> col-LSE -> broadcast lse_c subtract.
// ---------------------------------------------------------------------------
__global__ __launch_bounds__(512) void k_sinkhorn(
    const float* __restrict__ r0, float* __restrict__ out) {
  const int bh = blockIdx.x;
  const int tid = threadIdx.x;

  __shared__ float img[NB * (NB + 1)];   // stride 129, 66 KB
  __shared__ float lse_c[NB];

  const int row = tid >> 2;              // 0..127 (col index in col pass)
  const int qp = tid & 3;                // quarter

  float rr[32];
  {
    const float4* rp =
        (const float4*)(r0 + (size_t)bh * NB * NB + row * NB + qp * 32);
#pragma unroll
    for (int u = 0; u < 8; u++) {
      const float4 v = rp[u];
      rr[4 * u + 0] = v.x; rr[4 * u + 1] = v.y;
      rr[4 * u + 2] = v.z; rr[4 * u + 3] = v.w;
    }
  }

  for (int it = 0; it < 8; it++) {
    // ---- row logsumexp (pure registers + 2 shfl) ----
    float m = rr[0];
#pragma unroll
    for (int j = 1; j < 32; j++) m = fmaxf(m, rr[j]);
    m = fmaxf(m, __shfl_xor(m, 1));
    m = fmaxf(m, __shfl_xor(m, 2));
    float s = 0.f;
#pragma unroll
    for (int j = 0; j < 32; j++) s += __expf(rr[j] - m);
    s += __shfl_xor(s, 1);
    s += __shfl_xor(s, 2);
    const float lse = m + __logf(s);
#pragma unroll
    for (int j = 0; j < 32; j++) rr[j] -= lse;

    // ---- publish row-normalized values ----
#pragma unroll
    for (int j = 0; j < 32; j++) img[row * (NB + 1) + qp * 32 + j] = rr[j];
    __syncthreads();

    // ---- column logsumexp: col c = row; rows n = qp*32 + stagger(j) ----
    float tmp[32];
#pragma unroll
    for (int j = 0; j < 32; j++) {
      const int n = qp * 32 + ((j + qp * 8) & 31);
      tmp[j] = img[n * (NB + 1) + row];
    }
    float cm = tmp[0];
#pragma unroll
    for (int j = 1; j < 32; j++) cm = fmaxf(cm, tmp[j]);
    cm = fmaxf(cm, __shfl_xor(cm, 1));
    cm = fmaxf(cm, __shfl_xor(cm, 2));
    float cs = 0.f;
#pragma unroll
    for (int j = 0; j < 32; j++) cs += __expf(tmp[j] - cm);
    cs += __shfl_xor(cs, 1);
    cs += __shfl_xor(cs, 2);
    if (qp == 0) lse_c[row] = cm + __logf(cs);
    __syncthreads();

    // ---- subtract column lse (broadcast reads) ----
#pragma unroll
    for (int j = 0; j < 32; j++) rr[j] -= lse_c[qp * 32 + j];
  }

  // ---- output exp(r) ----
  {
    float4* op = (float4*)(out + (size_t)bh * NB * NB + row * NB + qp * 32);
#pragma unroll
    for (int u = 0; u < 8; u++) {
      float4 v;
      v.x = __expf(rr[4 * u + 0]);
      v.y = __expf(rr[4 * u + 1]);
      v.z = __expf(rr[4 * u + 2]);
      v.w = __expf(rr[4 * u + 3]);
      op[u] = v;
    }
  }
}

// ---------------------------------------------------------------------------
extern "C" void kernel_launch(void* const* d_in, const int* in_sizes, int n_in,
                              void* d_out, int out_size, void* d_ws, size_t ws_size,
                              hipStream_t stream) {
  const float* q = (const float*)d_in[0];
  const float* k = (const float*)d_in[1];
  const float* linear = (const float*)d_in[2];   // (1, 8, 128, 128)
  const int* seg = (const int*)d_in[3];          // (4, 16384)
  const float* gum = (const float*)d_in[4];      // (32, 128, 128)
  float* out = (float*)d_out;                    // (32, 128, 128) f32

  float* x = (float*)d_ws;                       // (32, 128, 128) f32 scratch
  int* bounds = (int*)(x + (size_t)BH * NB * DIM);  // (4, 129) int32
  float* r0 = out;                               // stage r0 in d_out (2 MB)

  k_bounds<<<B, 256, 0, stream>>>(seg, bounds);

  k_bucketsum<<<BH * NB / 4, 256, 0, stream>>>(q, k, bounds, x);

  dim3 g2(8, BH);
  k_matmul<<<g2, 256, 0, stream>>>(x, linear, gum, r0);

  k_sinkhorn<<<BH, 512, 0, stream>>>(r0, out);
}

// Round 9
// 373.411 us; speedup vs baseline: 1.0039x; 1.0039x over previous
//
#include <hip/hip_runtime.h>
#include <hip/hip_bf16.h>
#include <stdint.h>

// Problem constants (fixed by reference setup_inputs)
constexpr int HEADS = 8;
constexpr int B = 4;
constexpr int BH = B * HEADS;   // 32
constexpr int T = 16384;
constexpr int DH = 64;
constexpr int NB = 128;          // MAX_BUCKETS
constexpr int DIM = 128;         // 2*DH
constexpr float EPS = 1e-6f;
constexpr float INV_TEMP = 1.0f / 0.7f;

typedef float v2f __attribute__((ext_vector_type(2)));

// ---------------------------------------------------------------------------
// K0: bucket boundaries. seg[b] is sorted; start[b][m] = first index i with
// seg[b][i] >= m, for m in [0,128]. start[b][128] = T.
// ---------------------------------------------------------------------------
__global__ __launch_bounds__(256) void k_bounds(
    const int* __restrict__ seg, int* __restrict__ start) {
  const int b = blockIdx.x;
  const int tid = threadIdx.x;
  const int* s = seg + (size_t)b * T;
  for (int i = tid; i <= T; i += 256) {
    const int prev = (i == 0) ? -1 : s[i - 1];
    const int cur = (i == T) ? NB : s[i];
    for (int v = prev + 1; v <= cur; ++v) start[b * (NB + 1) + v] = i;
  }
}

// ---------------------------------------------------------------------------
// K1: bucket sums. One wave per (bh, m). Lanes 0..31 sum q rows (one float2
// per lane), lanes 32..63 sum k rows. The 16-row batch is loaded with an
// INLINE-ASM block: 16 global_load_dwordx2 from one VGPR-pair address with
// immediate offsets (u*256 bytes) and ONE s_waitcnt vmcnt(0) — guaranteeing
// 16 loads in flight per wave (the compiler was serializing at depth 1).
// Tail: one overlapping batch at tb=e-16 with per-row include weights.
// ---------------------------------------------------------------------------
#define LOAD16(ADDR)                                                        \
  asm volatile(                                                             \
      "global_load_dwordx2 %[o0],  %[a], off\n\t"                           \
      "global_load_dwordx2 %[o1],  %[a], off offset:256\n\t"                \
      "global_load_dwordx2 %[o2],  %[a], off offset:512\n\t"                \
      "global_load_dwordx2 %[o3],  %[a], off offset:768\n\t"                \
      "global_load_dwordx2 %[o4],  %[a], off offset:1024\n\t"               \
      "global_load_dwordx2 %[o5],  %[a], off offset:1280\n\t"               \
      "global_load_dwordx2 %[o6],  %[a], off offset:1536\n\t"               \
      "global_load_dwordx2 %[o7],  %[a], off offset:1792\n\t"               \
      "global_load_dwordx2 %[o8],  %[a], off offset:2048\n\t"               \
      "global_load_dwordx2 %[o9],  %[a], off offset:2304\n\t"               \
      "global_load_dwordx2 %[o10], %[a], off offset:2560\n\t"               \
      "global_load_dwordx2 %[o11], %[a], off offset:2816\n\t"               \
      "global_load_dwordx2 %[o12], %[a], off offset:3072\n\t"               \
      "global_load_dwordx2 %[o13], %[a], off offset:3328\n\t"               \
      "global_load_dwordx2 %[o14], %[a], off offset:3584\n\t"               \
      "global_load_dwordx2 %[o15], %[a], off offset:3840\n\t"               \
      "s_waitcnt vmcnt(0)"                                                  \
      : [o0] "=&v"(v0), [o1] "=&v"(v1), [o2] "=&v"(v2), [o3] "=&v"(v3),     \
        [o4] "=&v"(v4), [o5] "=&v"(v5), [o6] "=&v"(v6), [o7] "=&v"(v7),     \
        [o8] "=&v"(v8), [o9] "=&v"(v9), [o10] "=&v"(v10),                   \
        [o11] "=&v"(v11), [o12] "=&v"(v12), [o13] "=&v"(v13),               \
        [o14] "=&v"(v14), [o15] "=&v"(v15)                                  \
      : [a] "v"(ADDR)                                                       \
      : "memory")

__global__ __launch_bounds__(256) void k_bucketsum(
    const float* __restrict__ q, const float* __restrict__ k,
    const int* __restrict__ start, float* __restrict__ x) {
  const int wave = threadIdx.x >> 6;
  const int lane = threadIdx.x & 63;
  const int p = blockIdx.x * 4 + wave;   // (bh, m) pair index, 0..4095
  const int bh = p >> 7;
  const int m = p & 127;
  const int b = bh >> 3;

  const int s = start[b * (NB + 1) + m];
  const int e = start[b * (NB + 1) + m + 1];

  const int half = lane >> 5;            // 0 = q, 1 = k
  const int li = lane & 31;              // float2 index within row
  const float* basef = (half ? k : q) + (size_t)bh * T * DH;
  const uint64_t base_addr =
      (uint64_t)(uintptr_t)(basef) + (uint64_t)li * 8;

  float ax = 0.f, ay = 0.f;

  if (e - s >= 16) {
    int t = s;
    for (; t + 16 <= e; t += 16) {
      v2f v0, v1, v2, v3, v4, v5, v6, v7, v8, v9, v10, v11, v12, v13, v14, v15;
      const uint64_t a = base_addr + (uint64_t)t * 256;
      LOAD16(a);
      ax += (((v0.x + v1.x) + (v2.x + v3.x)) + ((v4.x + v5.x) + (v6.x + v7.x))) +
            (((v8.x + v9.x) + (v10.x + v11.x)) +
             ((v12.x + v13.x) + (v14.x + v15.x)));
      ay += (((v0.y + v1.y) + (v2.y + v3.y)) + ((v4.y + v5.y) + (v6.y + v7.y))) +
            (((v8.y + v9.y) + (v10.y + v11.y)) +
             ((v12.y + v13.y) + (v14.y + v15.y)));
    }
    if (t < e) {
      // overlapping final batch: rows tb..tb+15 where tb = e-16 >= s.
      // include row tb+u iff tb+u >= t, i.e. u >= d where d = t - tb in [1,15].
      const int tb = e - 16;
      const int d = t - tb;
      v2f v0, v1, v2, v3, v4, v5, v6, v7, v8, v9, v10, v11, v12, v13, v14, v15;
      const uint64_t a = base_addr + (uint64_t)tb * 256;
      LOAD16(a);
      if (d <= 1)  { ax += v1.x;  ay += v1.y; }
      if (d <= 2)  { ax += v2.x;  ay += v2.y; }
      if (d <= 3)  { ax += v3.x;  ay += v3.y; }
      if (d <= 4)  { ax += v4.x;  ay += v4.y; }
      if (d <= 5)  { ax += v5.x;  ay += v5.y; }
      if (d <= 6)  { ax += v6.x;  ay += v6.y; }
      if (d <= 7)  { ax += v7.x;  ay += v7.y; }
      if (d <= 8)  { ax += v8.x;  ay += v8.y; }
      if (d <= 9)  { ax += v9.x;  ay += v9.y; }
      if (d <= 10) { ax += v10.x; ay += v10.y; }
      if (d <= 11) { ax += v11.x; ay += v11.y; }
      if (d <= 12) { ax += v12.x; ay += v12.y; }
      if (d <= 13) { ax += v13.x; ay += v13.y; }
      if (d <= 14) { ax += v14.x; ay += v14.y; }
      { ax += v15.x; ay += v15.y; }      // d <= 15 always
    }
  } else {
    for (int t = s; t < e; ++t) {
      const float2 v = *(const float2*)(basef + (size_t)t * 64 + li * 2);
      ax += v.x;
      ay += v.y;
    }
  }

  float* op = x + ((size_t)bh * NB + m) * DIM + half * DH + li * 2;
  op[0] = ax;
  op[1] = ay;
}

// ---------------------------------------------------------------------------
// K2a: R = relu(x @ W), r0 = (log(R+eps) + gumbel)/temp. One block per
// (bh, 16-row chunk). x rows staged in LDS; W streamed from L1/L2.
// ---------------------------------------------------------------------------
__global__ __launch_bounds__(256) void k_matmul(
    const float* __restrict__ x, const float* __restrict__ linear,
    const float* __restrict__ gumbel, float* __restrict__ r0) {
  const int bh = blockIdx.y;
  const int n0 = blockIdx.x * 16;
  const int h = bh & 7;                  // bh % HEADS
  const int tid = threadIdx.x;

  __shared__ float xs[16][DIM];          // 8 KB

  const float4* xp = (const float4*)(x + ((size_t)bh * NB + n0) * DIM);
  for (int i = tid; i < 16 * 32; i += 256) {
    const float4 v = xp[i];
    const int n = i >> 5, d4 = i & 31;
    xs[n][d4 * 4 + 0] = v.x;
    xs[n][d4 * 4 + 1] = v.y;
    xs[n][d4 * 4 + 2] = v.z;
    xs[n][d4 * 4 + 3] = v.w;
  }
  __syncthreads();

  const int mt = tid & 31;               // output col float4
  const int rp = tid >> 5;               // 0..7 row pair
  const int ra = rp * 2;

  float4 a0 = make_float4(0.f, 0.f, 0.f, 0.f);
  float4 a1 = make_float4(0.f, 0.f, 0.f, 0.f);
  const float4* Wp = (const float4*)(linear + (size_t)h * DIM * NB);
  for (int d4 = 0; d4 < 32; d4++) {
    const float4 xv0 = *(const float4*)&xs[ra][d4 * 4];
    const float4 xv1 = *(const float4*)&xs[ra + 1][d4 * 4];
    const float4 w0 = Wp[(d4 * 4 + 0) * 32 + mt];
    const float4 w1 = Wp[(d4 * 4 + 1) * 32 + mt];
    const float4 w2 = Wp[(d4 * 4 + 2) * 32 + mt];
    const float4 w3 = Wp[(d4 * 4 + 3) * 32 + mt];
    a0.x += xv0.x * w0.x + xv0.y * w1.x + xv0.z * w2.x + xv0.w * w3.x;
    a0.y += xv0.x * w0.y + xv0.y * w1.y + xv0.z * w2.y + xv0.w * w3.y;
    a0.z += xv0.x * w0.z + xv0.y * w1.z + xv0.z * w2.z + xv0.w * w3.z;
    a0.w += xv0.x * w0.w + xv0.y * w1.w + xv0.z * w2.w + xv0.w * w3.w;
    a1.x += xv1.x * w0.x + xv1.y * w1.x + xv1.z * w2.x + xv1.w * w3.x;
    a1.y += xv1.x * w0.y + xv1.y * w1.y + xv1.z * w2.y + xv1.w * w3.y;
    a1.z += xv1.x * w0.z + xv1.y * w1.z + xv1.z * w2.z + xv1.w * w3.z;
    a1.w += xv1.x * w0.w + xv1.y * w1.w + xv1.z * w2.w + xv1.w * w3.w;
  }

  const float4* gp = (const float4*)(gumbel + ((size_t)bh * NB + n0) * NB);
  float4* op = (float4*)(r0 + ((size_t)bh * NB + n0) * NB);

  auto xform = [](float a, float u) {
    const float R = fmaxf(a, 0.f);
    const float g = -__logf(-__logf(u + EPS) + EPS);
    return (__logf(R + EPS) + g) * INV_TEMP;
  };
  {
    const float4 u = gp[(size_t)ra * 32 + mt];
    float4 o;
    o.x = xform(a0.x, u.x); o.y = xform(a0.y, u.y);
    o.z = xform(a0.z, u.z); o.w = xform(a0.w, u.w);
    op[(size_t)ra * 32 + mt] = o;
  }
  {
    const float4 u = gp[(size_t)(ra + 1) * 32 + mt];
    float4 o;
    o.x = xform(a1.x, u.x); o.y = xform(a1.y, u.y);
    o.z = xform(a1.z, u.z); o.w = xform(a1.w, u.w);
    op[(size_t)(ra + 1) * 32 + mt] = o;
  }
}

// ---------------------------------------------------------------------------
// K2b: 8 Sinkhorn iterations + exp. One block (512 threads) per bh.
// Row state in REGISTERS: thread (row=tid>>2, qp=tid&3) owns r[row][qp*32+j].
// ---------------------------------------------------------------------------
__global__ __launch_bounds__(512) void k_sinkhorn(
    const float* __restrict__ r0, float* __restrict__ out) {
  const int bh = blockIdx.x;
  const int tid = threadIdx.x;

  __shared__ float img[NB * (NB + 1)];   // stride 129, 66 KB
  __shared__ float lse_c[NB];

  const int row = tid >> 2;              // 0..127 (col index in col pass)
  const int qp = tid & 3;                // quarter

  float rr[32];
  {
    const float4* rp =
        (const float4*)(r0 + (size_t)bh * NB * NB + row * NB + qp * 32);
#pragma unroll
    for (int u = 0; u < 8; u++) {
      const float4 v = rp[u];
      rr[4 * u + 0] = v.x; rr[4 * u + 1] = v.y;
      rr[4 * u + 2] = v.z; rr[4 * u + 3] = v.w;
    }
  }

  for (int it = 0; it < 8; it++) {
    // ---- row logsumexp (pure registers + 2 shfl) ----
    float m = rr[0];
#pragma unroll
    for (int j = 1; j < 32; j++) m = fmaxf(m, rr[j]);
    m = fmaxf(m, __shfl_xor(m, 1));
    m = fmaxf(m, __shfl_xor(m, 2));
    float s = 0.f;
#pragma unroll
    for (int j = 0; j < 32; j++) s += __expf(rr[j] - m);
    s += __shfl_xor(s, 1);
    s += __shfl_xor(s, 2);
    const float lse = m + __logf(s);
#pragma unroll
    for (int j = 0; j < 32; j++) rr[j] -= lse;

    // ---- publish row-normalized values ----
#pragma unroll
    for (int j = 0; j < 32; j++) img[row * (NB + 1) + qp * 32 + j] = rr[j];
    __syncthreads();

    // ---- column logsumexp: col c = row; rows n = qp*32 + stagger(j) ----
    float tmp[32];
#pragma unroll
    for (int j = 0; j < 32; j++) {
      const int n = qp * 32 + ((j + qp * 8) & 31);
      tmp[j] = img[n * (NB + 1) + row];
    }
    float cm = tmp[0];
#pragma unroll
    for (int j = 1; j < 32; j++) cm = fmaxf(cm, tmp[j]);
    cm = fmaxf(cm, __shfl_xor(cm, 1));
    cm = fmaxf(cm, __shfl_xor(cm, 2));
    float cs = 0.f;
#pragma unroll
    for (int j = 0; j < 32; j++) cs += __expf(tmp[j] - cm);
    cs += __shfl_xor(cs, 1);
    cs += __shfl_xor(cs, 2);
    if (qp == 0) lse_c[row] = cm + __logf(cs);
    __syncthreads();

    // ---- subtract column lse (broadcast reads) ----
#pragma unroll
    for (int j = 0; j < 32; j++) rr[j] -= lse_c[qp * 32 + j];
  }

  // ---- output exp(r) ----
  {
    float4* op = (float4*)(out + (size_t)bh * NB * NB + row * NB + qp * 32);
#pragma unroll
    for (int u = 0; u < 8; u++) {
      float4 v;
      v.x = __expf(rr[4 * u + 0]);
      v.y = __expf(rr[4 * u + 1]);
      v.z = __expf(rr[4 * u + 2]);
      v.w = __expf(rr[4 * u + 3]);
      op[u] = v;
    }
  }
}

// ---------------------------------------------------------------------------
extern "C" void kernel_launch(void* const* d_in, const int* in_sizes, int n_in,
                              void* d_out, int out_size, void* d_ws, size_t ws_size,
                              hipStream_t stream) {
  const float* q = (const float*)d_in[0];
  const float* k = (const float*)d_in[1];
  const float* linear = (const float*)d_in[2];   // (1, 8, 128, 128)
  const int* seg = (const int*)d_in[3];          // (4, 16384)
  const float* gum = (const float*)d_in[4];      // (32, 128, 128)
  float* out = (float*)d_out;                    // (32, 128, 128) f32

  float* x = (float*)d_ws;                       // (32, 128, 128) f32 scratch
  int* bounds = (int*)(x + (size_t)BH * NB * DIM);  // (4, 129) int32
  float* r0 = out;                               // stage r0 in d_out (2 MB)

  k_bounds<<<B, 256, 0, stream>>>(seg, bounds);

  k_bucketsum<<<BH * NB / 4, 256, 0, stream>>>(q, k, bounds, x);

  dim3 g2(8, BH);
  k_matmul<<<g2, 256, 0, stream>>>(x, linear, gum, r0);

  k_sinkhorn<<<BH, 512, 0, stream>>>(r0, out);
}